// Round 11
// baseline (121.519 us; speedup 1.0000x reference)
//
#include <hip/hip_runtime.h>

// WeatherLSTM: B=4096 indep. sequences, T=512 steps, H=10, I=O=1.
// R10 = R9 with the permlane32_swap selection fixed. permlane32_swap(v,v)
// returns {high-half bcast, low-half bcast} in HW-convention order; the
// "partner value" needs r[0] on one half and r[1] on the other -> PER-LANE
// cndmask selection (R9's wave-"uniform" probe diverged the two halves into
// different template bodies, breaking the lockstep the swap requires).
// Layout: 32 lanes/element, split by gate-pair, UNIFORM instruction stream:
//   half0 (lane<32): gates i,f -> real c' chain
//   half1 (lane>=32): gates g,o -> real h chain
// Off-role half computes bounded garbage (contractive: |c'|<|c|/(1+po)+1)
// ending in a dump LDS slot (never read). Cross-half traffic: 2 swaps/step.
// h all-gather: 1 ds_write_b32 (half1 k<10 -> slot k, others -> dump) +
// float4/float2 broadcast reads, all wave-local (element = lanes {k, k+32}).
// 4096 elems x 32 lanes = 2048 waves = 2/SIMD -> chain stalls hidden.
// Math (R8-verified): prescaled weights (-L sigmoid rows, -2L tanh row);
//   c' = (c*(1+pi)(1+pg) + (1-pg)(1+pf)) * rcp((1+pf)(1+pi)(1+pg))
//   h  = (1-pc) * rcp((1+po)(1+pc)),  pc = exp2(-2L*c')

#define NLOG2E (-1.4426950408889634f)

typedef float f4v __attribute__((ext_vector_type(4)));
typedef float f2v __attribute__((ext_vector_type(2)));

__device__ __forceinline__ float swap_rx(float v, bool pick0) {
    // partner (lane^32) value; pick0 is per-lane, loop-invariant -> v_cndmask
    auto r = __builtin_amdgcn_permlane32_swap(
        __float_as_uint(v), __float_as_uint(v), false, false);
    return __uint_as_float(pick0 ? r[0] : r[1]);
}

__global__ __launch_bounds__(256, 2) void WeatherLSTM_kernel(
    const float* __restrict__ x,     // [B, T, 1]
    const float* __restrict__ W_ih,  // [40, 1]
    const float* __restrict__ W_hh,  // [40, 10]
    const float* __restrict__ b_ih,  // [40]
    const float* __restrict__ b_hh,  // [40]
    const float* __restrict__ W_fc,  // [1, 10]
    const float* __restrict__ b_fc,  // [1]
    float* __restrict__ out,         // [B, 1]
    int T)
{
    __shared__ float hsh[8][12];     // 8 elems/block x (10 h + dump + pad)
    const int tid  = threadIdx.x;    // 256 = 4 waves; 2 elements per wave
    const int lane = tid & 63;
    const int wav  = tid >> 6;
    const int k    = lane & 15;      // hidden unit; active iff k < 10
    const int ei   = (lane >> 4) & 1;
    const int half = lane >> 5;      // 0: gates (i,f) ; 1: gates (g,o)
    const int eib  = wav * 2 + ei;
    const long e   = (long)blockIdx.x * 8 + eib;
    const bool act = (k < 10);

    // Probe which result slot carries the HIGH-half broadcast (wave-uniform),
    // then build the per-lane partner selector.
    auto pr = __builtin_amdgcn_permlane32_swap((unsigned)lane, (unsigned)lane,
                                               false, false);
    const bool hibc  = (__builtin_amdgcn_readfirstlane((int)pr[0]) == 32);
    const bool pick0 = ((lane < 32) == hibc);

    // This half's two gate rows: t0 = 2*half (i or g), t1 = t0+1 (f or o).
    // Prescale: -L for sigmoid rows (i,f,o), -2L for the tanh row (g).
    const int t0 = 2 * half, t1 = t0 + 1;
    const float sc0 = (t0 == 2) ? (2.0f * NLOG2E) : NLOG2E;
    const float sc1 = NLOG2E;
    const int g0 = t0 * 10 + k, g1 = t1 * 10 + k;
    float wh0[10], wh1[10];
    const float wx0 = act ? W_ih[g0] * sc0 : 0.0f;
    const float wx1 = act ? W_ih[g1] * sc1 : 0.0f;
    const float bb0 = act ? (b_ih[g0] + b_hh[g0]) * sc0 : 0.0f;
    const float bb1 = act ? (b_ih[g1] + b_hh[g1]) * sc1 : 0.0f;
    #pragma unroll
    for (int j = 0; j < 10; ++j) {
        wh0[j] = act ? W_hh[g0 * 10 + j] * sc0 : 0.0f;
        wh1[j] = act ? W_hh[g1 * 10 + j] * sc1 : 0.0f;
    }
    // Inactive lanes (k>=10): a=0 -> p=1 -> bounded chain, writes go to dump.

    float* hrow = &hsh[eib][0];
    const bool writeok = (half == 1) && act;
    float* wptr = hrow + (writeok ? k : 10);   // dump slot 10, never read

    float h[10];
    #pragma unroll
    for (int j = 0; j < 10; ++j) h[j] = 0.0f;
    float c = 0.0f;

    const float* xe = x + e * (long)T;
    f4v xv = *reinterpret_cast<const f4v*>(xe);
    for (int s0i = 0; s0i < T; s0i += 4) {
        const int snext = (s0i + 4 < T) ? (s0i + 4) : s0i;   // clamped prefetch
        const f4v xnext = *reinterpret_cast<const f4v*>(xe + snext);
        #pragma unroll
        for (int ss = 0; ss < 4; ++ss) {
            const float xt = xv[ss];

            // two gate dots (this half's pair), 4 independent chains
            float a0A = fmaf(xt, wx0, bb0);
            float a1A = fmaf(xt, wx1, bb1);
            float a0B = h[5] * wh0[5];
            float a1B = h[5] * wh1[5];
            #pragma unroll
            for (int j = 0; j < 5; ++j) {
                a0A = fmaf(h[j], wh0[j], a0A);
                a1A = fmaf(h[j], wh1[j], a1A);
            }
            #pragma unroll
            for (int j = 6; j < 10; ++j) {
                a0B = fmaf(h[j], wh0[j], a0B);
                a1B = fmaf(h[j], wh1[j], a1B);
            }
            const float p0 = __builtin_amdgcn_exp2f(a0A + a0B); // pi | pg
            const float p1 = __builtin_amdgcn_exp2f(a1A + a1B); // pf | po

            // half0 receives pg (real); half1 receives pi (bounded garbage)
            const float s0 = swap_rx(p0, pick0);

            // uniform F: half0 -> real c'; half1 -> bounded garbage (unused)
            const float qa = 1.0f + p0, qb = 1.0f + p1;
            const float qs = 1.0f + s0, m  = 1.0f - s0;
            const float A   = qa * qs;
            const float num = fmaf(c, A, m * qb);
            c = num * __builtin_amdgcn_rcpf(A * qb);
            const float pc = __builtin_amdgcn_exp2f(c * (2.0f * NLOG2E));

            // half1 receives real pc; half0 receives garbage
            const float s1 = swap_rx(pc, pick0);

            // uniform h: half1 -> real hown (qb = 1+po local); half0 garbage
            const float qc = 1.0f + s1, mc = 1.0f - s1;
            const float hown = mc * __builtin_amdgcn_rcpf(qb * qc);

            // gather: real lanes (half1, k<10) write slot k; others dump slot
            *wptr = hown;
            const f4v r0 = *reinterpret_cast<const f4v*>(hrow);
            const f4v r1 = *reinterpret_cast<const f4v*>(hrow + 4);
            const f2v r2 = *reinterpret_cast<const f2v*>(hrow + 8);
            h[0] = r0[0]; h[1] = r0[1]; h[2] = r0[2]; h[3] = r0[3];
            h[4] = r1[0]; h[5] = r1[1]; h[6] = r1[2]; h[7] = r1[3];
            h[8] = r2[0]; h[9] = r2[1];
        }
        xv = xnext;
    }

    if (half == 0 && k == 0) {
        float o = b_fc[0];
        #pragma unroll
        for (int j = 0; j < 10; ++j)
            o = fmaf(h[j], W_fc[j], o);
        out[e] = o;
    }
}

extern "C" void kernel_launch(void* const* d_in, const int* in_sizes, int n_in,
                              void* d_out, int out_size, void* d_ws, size_t ws_size,
                              hipStream_t stream) {
    const float* x    = (const float*)d_in[0];
    const float* W_ih = (const float*)d_in[1];
    const float* W_hh = (const float*)d_in[2];
    const float* b_ih = (const float*)d_in[3];
    const float* b_hh = (const float*)d_in[4];
    const float* W_fc = (const float*)d_in[5];
    const float* b_fc = (const float*)d_in[6];
    float* out = (float*)d_out;

    const int B = out_size;          // 4096
    const int T = in_sizes[0] / B;   // 512

    dim3 grid(B / 8), block(256);    // 8 elems/block, 512 blocks, 2 waves/SIMD
    hipLaunchKernelGGL(WeatherLSTM_kernel, grid, block, 0, stream,
                       x, W_ih, W_hh, b_ih, b_hh, W_fc, b_fc, out, T);
}

// Round 12
// 115.632 us; speedup vs baseline: 1.0509x; 1.0509x over previous
//
#include <hip/hip_runtime.h>

// WeatherLSTM: B=4096 indep. sequences, T=512 steps, H=10, I=O=1.
// R11 = R6/R8's issue-optimal 16-lane layout with the LDS h-gather replaced
// by a DPP row_ror all-gather (R7's idea, scalar f32 dots instead of the
// non-existent scalar-operand pk form).
//   lane = hidden unit k (16 lanes/elem, 4 elems/wave, 1024 waves = 1/SIMD)
//   per step: hs[0]=hown; hs[i]=v_mov_dpp row_ror:i (15 independent, ~2cy,
//   VALU pipe) -> kills the ~120-150cy LDS write->read RAW chain of R6.
// Dots run over 16 rotated slots (6 zero-weight lanes-worth of padding);
// slot->hidden-index permutation folded into the weight layout at setup.
// Rotation direction runtime-probed once (wave-uniform); epilogue computes
// both direction variants with STATIC register indexing (no scratch demotion).
// Math (R8-verified): prescaled weights (-L sigmoid rows, -2L tanh row);
//   c' = (c*(1+pi)(1+pg) + (1-pg)(1+pf)) * rcp((1+pf)(1+pi)(1+pg))
//   h  = (1-pc) * rcp((1+po)(1+pc)),  pc = exp2(-2L*c')
// -> 5 exp2 + 2 rcp per step. No LDS anywhere.

#define NLOG2E (-1.4426950408889634f)

typedef float f4v __attribute__((ext_vector_type(4)));

template<int I>
__device__ __forceinline__ float rorf(float v) {
    // v_mov_b32_dpp row_ror:I (16-lane rows; ctrl = 0x120 + I)
    return __int_as_float(__builtin_amdgcn_update_dpp(
        __float_as_int(v), __float_as_int(v), 0x120 + I, 0xF, 0xF, false));
}

__global__ __launch_bounds__(256, 1) void WeatherLSTM_kernel(
    const float* __restrict__ x,     // [B, T, 1]
    const float* __restrict__ W_ih,  // [40, 1]
    const float* __restrict__ W_hh,  // [40, 10]
    const float* __restrict__ b_ih,  // [40]
    const float* __restrict__ b_hh,  // [40]
    const float* __restrict__ W_fc,  // [1, 10]
    const float* __restrict__ b_fc,  // [1]
    float* __restrict__ out,         // [B, 1]
    int T)
{
    const int tid = threadIdx.x;     // 256 = 16 groups of 16 lanes
    const int k   = tid & 15;        // hidden unit; active iff k < 10
    const int grp = tid >> 4;
    const long e  = (long)blockIdx.x * 16 + grp;
    const bool act = (k < 10);

    // Probe row_ror direction once (wave-uniform: every 16-lane row holds
    // 0..15): slot i gets h_{(k+i)&15} if "plus", else h_{(k-i)&15}.
    const int probe = __builtin_amdgcn_update_dpp(k, k, 0x121, 0xF, 0xF, false);
    const bool plus = (probe == ((k + 1) & 15));

    // Rotated, prescaled weights: wh[t][i] multiplies slot i (= rotated h).
    // Row scale: -L for sigmoid gates (i,f,o), -2L for the tanh gate (g).
    float wh[4][16], wx[4], bb[4];
    #pragma unroll
    for (int t = 0; t < 4; ++t) {
        const float s = (t == 2) ? (2.0f * NLOG2E) : NLOG2E;
        const int g = t * 10 + k;
        wx[t] = act ? W_ih[g] * s : 0.0f;
        bb[t] = act ? (b_ih[g] + b_hh[g]) * s : 0.0f;
        #pragma unroll
        for (int i = 0; i < 16; ++i) {
            const int j = plus ? ((k + i) & 15) : ((k - i + 16) & 15);
            const bool v = act && (j < 10);
            wh[t][i] = v ? W_hh[g * 10 + j] * s : 0.0f;
        }
    }
    // Inactive lanes (k>=10): all weights 0 -> args 0 -> p*=1 -> mg=0 ->
    // c'=c/2 stays 0, hown=0 exactly; their slots feed zero weights. Safe.

    float hs[16];                    // slot i = rotated h (see probe comment)
    #pragma unroll
    for (int i = 0; i < 16; ++i) hs[i] = 0.0f;
    float c = 0.0f;

    const float* xe = x + e * (long)T;
    f4v xv = *reinterpret_cast<const f4v*>(xe);
    for (int s0i = 0; s0i < T; s0i += 4) {
        const int snext = (s0i + 4 < T) ? (s0i + 4) : s0i;   // clamped prefetch
        const f4v xnext = *reinterpret_cast<const f4v*>(xe + snext);
        #pragma unroll
        for (int ss = 0; ss < 4; ++ss) {
            const float xt = xv[ss];

            // 4 gate dots over 16 slots, split A/B halves -> 8 indep chains
            float accA[4], accB[4];
            #pragma unroll
            for (int t = 0; t < 4; ++t) {
                accA[t] = fmaf(xt, wx[t], bb[t]);
                accB[t] = hs[8] * wh[t][8];
            }
            #pragma unroll
            for (int i = 0; i < 8; ++i) {
                #pragma unroll
                for (int t = 0; t < 4; ++t)
                    accA[t] = fmaf(hs[i], wh[t][i], accA[t]);
            }
            #pragma unroll
            for (int i = 9; i < 16; ++i) {
                #pragma unroll
                for (int t = 0; t < 4; ++t)
                    accB[t] = fmaf(hs[i], wh[t][i], accB[t]);
            }
            const float pi = __builtin_amdgcn_exp2f(accA[0] + accB[0]);
            const float pf = __builtin_amdgcn_exp2f(accA[1] + accB[1]);
            const float pg = __builtin_amdgcn_exp2f(accA[2] + accB[2]);
            const float po = __builtin_amdgcn_exp2f(accA[3] + accB[3]);

            // c' = (c*(1+pi)(1+pg) + (1-pg)(1+pf)) / ((1+pf)(1+pi)(1+pg))
            const float qi = 1.0f + pi, qf = 1.0f + pf, qg = 1.0f + pg;
            const float mg = 1.0f - pg;
            const float A   = qi * qg;
            const float num = fmaf(c, A, mg * qf);
            c = num * __builtin_amdgcn_rcpf(A * qf);

            // h = (1-pc) / ((1+po)(1+pc)),  pc = exp2(-2L*c)
            const float pc = __builtin_amdgcn_exp2f(c * (2.0f * NLOG2E));
            const float qo = 1.0f + po, qc = 1.0f + pc, mc = 1.0f - pc;
            const float hown = mc * __builtin_amdgcn_rcpf(qo * qc);

            // DPP all-gather: 15 independent row_ror movs (no LDS, no DS pipe)
            hs[0]  = hown;
            hs[1]  = rorf<1>(hown);   hs[2]  = rorf<2>(hown);
            hs[3]  = rorf<3>(hown);   hs[4]  = rorf<4>(hown);
            hs[5]  = rorf<5>(hown);   hs[6]  = rorf<6>(hown);
            hs[7]  = rorf<7>(hown);   hs[8]  = rorf<8>(hown);
            hs[9]  = rorf<9>(hown);   hs[10] = rorf<10>(hown);
            hs[11] = rorf<11>(hown);  hs[12] = rorf<12>(hown);
            hs[13] = rorf<13>(hown);  hs[14] = rorf<14>(hown);
            hs[15] = rorf<15>(hown);
        }
        xv = xnext;
    }

    if (k == 0) {
        // Static-index epilogues for both rotation conventions (avoid runtime
        // indexing of the register array -> scratch demotion).
        float op = b_fc[0], om = b_fc[0];
        #pragma unroll
        for (int j = 0; j < 10; ++j) {
            op = fmaf(hs[j], W_fc[j], op);                 // plus:  h_j at slot j
        }
        om = fmaf(hs[0],  W_fc[0], om);                    // minus: h_j at (16-j)&15
        om = fmaf(hs[15], W_fc[1], om);  om = fmaf(hs[14], W_fc[2], om);
        om = fmaf(hs[13], W_fc[3], om);  om = fmaf(hs[12], W_fc[4], om);
        om = fmaf(hs[11], W_fc[5], om);  om = fmaf(hs[10], W_fc[6], om);
        om = fmaf(hs[9],  W_fc[7], om);  om = fmaf(hs[8],  W_fc[8], om);
        om = fmaf(hs[7],  W_fc[9], om);
        out[e] = plus ? op : om;
    }
}

extern "C" void kernel_launch(void* const* d_in, const int* in_sizes, int n_in,
                              void* d_out, int out_size, void* d_ws, size_t ws_size,
                              hipStream_t stream) {
    const float* x    = (const float*)d_in[0];
    const float* W_ih = (const float*)d_in[1];
    const float* W_hh = (const float*)d_in[2];
    const float* b_ih = (const float*)d_in[3];
    const float* b_hh = (const float*)d_in[4];
    const float* W_fc = (const float*)d_in[5];
    const float* b_fc = (const float*)d_in[6];
    float* out = (float*)d_out;

    const int B = out_size;          // 4096
    const int T = in_sizes[0] / B;   // 512

    dim3 grid(B / 16), block(256);   // 16 elems/block, 256 blocks = 1 per CU
    hipLaunchKernelGGL(WeatherLSTM_kernel, grid, block, 0, stream,
                       x, W_ih, W_hh, b_ih, b_hh, W_fc, b_fc, out, T);
}

// Round 13
// 104.661 us; speedup vs baseline: 1.1611x; 1.1048x over previous
//
#include <hip/hip_runtime.h>

// WeatherLSTM: B=4096 indep. sequences, T=512 steps, H=10, I=O=1.
// R12 = R11 (DPP row_ror h-gather, 16-lane layout, fused-rcp math) with the
// register-allocation handicap removed:
//  1) amdgpu_waves_per_eu(1,1): occupancy is structurally 1 wave/SIMD (1024
//     waves on 1024 SIMDs), so capping waves/EU at 1 is free and lets the
//     allocator hold wh[4][16]+hs[16] (~114 regs) instead of spilling
//     (R11: VGPR_Count=64 with ~90 cy/step of unexplained VALU shuttle work).
//  2) hs[i] = update_dpp(old=hs[i], src=hown): ties old to dest so each
//     gather slot is a single v_mov_b32_dpp (R11's old=src forced a copy).
// Math (R8-verified): prescaled weights (-L sigmoid rows, -2L tanh row);
//   c' = (c*(1+pi)(1+pg) + (1-pg)(1+pf)) * rcp((1+pf)(1+pi)(1+pg))
//   h  = (1-pc) * rcp((1+po)(1+pc)),  pc = exp2(-2L*c')
// -> 5 exp2 + 2 rcp per step. No LDS anywhere.

#define NLOG2E (-1.4426950408889634f)

typedef float f4v __attribute__((ext_vector_type(4)));

template<int I>
__device__ __forceinline__ float rorf(float old, float v) {
    // v_mov_b32_dpp row_ror:I (16-lane rows; ctrl = 0x120 + I); all lanes
    // enabled -> old only serves to let regalloc tie dest = old.
    return __int_as_float(__builtin_amdgcn_update_dpp(
        __float_as_int(old), __float_as_int(v), 0x120 + I, 0xF, 0xF, false));
}

__global__ __launch_bounds__(256)
__attribute__((amdgpu_waves_per_eu(1, 1)))
void WeatherLSTM_kernel(
    const float* __restrict__ x,     // [B, T, 1]
    const float* __restrict__ W_ih,  // [40, 1]
    const float* __restrict__ W_hh,  // [40, 10]
    const float* __restrict__ b_ih,  // [40]
    const float* __restrict__ b_hh,  // [40]
    const float* __restrict__ W_fc,  // [1, 10]
    const float* __restrict__ b_fc,  // [1]
    float* __restrict__ out,         // [B, 1]
    int T)
{
    const int tid = threadIdx.x;     // 256 = 16 groups of 16 lanes
    const int k   = tid & 15;        // hidden unit; active iff k < 10
    const int grp = tid >> 4;
    const long e  = (long)blockIdx.x * 16 + grp;
    const bool act = (k < 10);

    // Probe row_ror direction once (wave-uniform: every 16-lane row holds
    // 0..15): slot i gets h_{(k+i)&15} if "plus", else h_{(k-i)&15}.
    const int probe = __builtin_amdgcn_update_dpp(k, k, 0x121, 0xF, 0xF, false);
    const bool plus = (probe == ((k + 1) & 15));

    // Rotated, prescaled weights: wh[t][i] multiplies slot i (= rotated h).
    // Row scale: -L for sigmoid gates (i,f,o), -2L for the tanh gate (g).
    float wh[4][16], wx[4], bb[4];
    #pragma unroll
    for (int t = 0; t < 4; ++t) {
        const float s = (t == 2) ? (2.0f * NLOG2E) : NLOG2E;
        const int g = t * 10 + k;
        wx[t] = act ? W_ih[g] * s : 0.0f;
        bb[t] = act ? (b_ih[g] + b_hh[g]) * s : 0.0f;
        #pragma unroll
        for (int i = 0; i < 16; ++i) {
            const int j = plus ? ((k + i) & 15) : ((k - i + 16) & 15);
            const bool v = act && (j < 10);
            wh[t][i] = v ? W_hh[g * 10 + j] * s : 0.0f;
        }
    }
    // Inactive lanes (k>=10): all weights 0 -> args 0 -> p*=1 -> mg=0 ->
    // c'=c/2 stays 0, hown=0 exactly; their slots feed zero weights. Safe.

    float hs[16];                    // slot i = rotated h (see probe comment)
    #pragma unroll
    for (int i = 0; i < 16; ++i) hs[i] = 0.0f;
    float c = 0.0f;

    const float* xe = x + e * (long)T;
    f4v xv = *reinterpret_cast<const f4v*>(xe);
    for (int s0i = 0; s0i < T; s0i += 4) {
        const int snext = (s0i + 4 < T) ? (s0i + 4) : s0i;   // clamped prefetch
        const f4v xnext = *reinterpret_cast<const f4v*>(xe + snext);
        #pragma unroll
        for (int ss = 0; ss < 4; ++ss) {
            const float xt = xv[ss];

            // 4 gate dots over 16 slots, split A/B halves -> 8 indep chains
            float accA[4], accB[4];
            #pragma unroll
            for (int t = 0; t < 4; ++t) {
                accA[t] = fmaf(xt, wx[t], bb[t]);
                accB[t] = hs[8] * wh[t][8];
            }
            #pragma unroll
            for (int i = 0; i < 8; ++i) {
                #pragma unroll
                for (int t = 0; t < 4; ++t)
                    accA[t] = fmaf(hs[i], wh[t][i], accA[t]);
            }
            #pragma unroll
            for (int i = 9; i < 16; ++i) {
                #pragma unroll
                for (int t = 0; t < 4; ++t)
                    accB[t] = fmaf(hs[i], wh[t][i], accB[t]);
            }
            const float pi = __builtin_amdgcn_exp2f(accA[0] + accB[0]);
            const float pf = __builtin_amdgcn_exp2f(accA[1] + accB[1]);
            const float pg = __builtin_amdgcn_exp2f(accA[2] + accB[2]);
            const float po = __builtin_amdgcn_exp2f(accA[3] + accB[3]);

            // c' = (c*(1+pi)(1+pg) + (1-pg)(1+pf)) / ((1+pf)(1+pi)(1+pg))
            const float qi = 1.0f + pi, qf = 1.0f + pf, qg = 1.0f + pg;
            const float mg = 1.0f - pg;
            const float A   = qi * qg;
            const float num = fmaf(c, A, mg * qf);
            c = num * __builtin_amdgcn_rcpf(A * qf);

            // h = (1-pc) / ((1+po)(1+pc)),  pc = exp2(-2L*c)
            const float pc = __builtin_amdgcn_exp2f(c * (2.0f * NLOG2E));
            const float qo = 1.0f + po, qc = 1.0f + pc, mc = 1.0f - pc;
            const float hown = mc * __builtin_amdgcn_rcpf(qo * qc);

            // DPP all-gather: 15 single v_mov_dpp (dest tied to old)
            hs[0]  = hown;
            hs[1]  = rorf<1>(hs[1],  hown);  hs[2]  = rorf<2>(hs[2],  hown);
            hs[3]  = rorf<3>(hs[3],  hown);  hs[4]  = rorf<4>(hs[4],  hown);
            hs[5]  = rorf<5>(hs[5],  hown);  hs[6]  = rorf<6>(hs[6],  hown);
            hs[7]  = rorf<7>(hs[7],  hown);  hs[8]  = rorf<8>(hs[8],  hown);
            hs[9]  = rorf<9>(hs[9],  hown);  hs[10] = rorf<10>(hs[10], hown);
            hs[11] = rorf<11>(hs[11], hown); hs[12] = rorf<12>(hs[12], hown);
            hs[13] = rorf<13>(hs[13], hown); hs[14] = rorf<14>(hs[14], hown);
            hs[15] = rorf<15>(hs[15], hown);
        }
        xv = xnext;
    }

    if (k == 0) {
        // Static-index epilogues for both rotation conventions (avoid runtime
        // indexing of the register array -> scratch demotion).
        float op = b_fc[0], om = b_fc[0];
        #pragma unroll
        for (int j = 0; j < 10; ++j)
            op = fmaf(hs[j], W_fc[j], op);                 // plus: h_j at slot j
        om = fmaf(hs[0],  W_fc[0], om);                    // minus: h_j at (16-j)&15
        om = fmaf(hs[15], W_fc[1], om);  om = fmaf(hs[14], W_fc[2], om);
        om = fmaf(hs[13], W_fc[3], om);  om = fmaf(hs[12], W_fc[4], om);
        om = fmaf(hs[11], W_fc[5], om);  om = fmaf(hs[10], W_fc[6], om);
        om = fmaf(hs[9],  W_fc[7], om);  om = fmaf(hs[8],  W_fc[8], om);
        om = fmaf(hs[7],  W_fc[9], om);
        out[e] = plus ? op : om;
    }
}

extern "C" void kernel_launch(void* const* d_in, const int* in_sizes, int n_in,
                              void* d_out, int out_size, void* d_ws, size_t ws_size,
                              hipStream_t stream) {
    const float* x    = (const float*)d_in[0];
    const float* W_ih = (const float*)d_in[1];
    const float* W_hh = (const float*)d_in[2];
    const float* b_ih = (const float*)d_in[3];
    const float* b_hh = (const float*)d_in[4];
    const float* W_fc = (const float*)d_in[5];
    const float* b_fc = (const float*)d_in[6];
    float* out = (float*)d_out;

    const int B = out_size;          // 4096
    const int T = in_sizes[0] / B;   // 512

    dim3 grid(B / 16), block(256);   // 16 elems/block, 256 blocks = 1 per CU
    hipLaunchKernelGGL(WeatherLSTM_kernel, grid, block, 0, stream,
                       x, W_ih, W_hh, b_ih, b_hh, W_fc, b_fc, out, T);
}